// Round 1
// baseline (1627.371 us; speedup 1.0000x reference)
//
#include <hip/hip_runtime.h>

// Problem constants (setup_inputs): B=8, C=256, H=128, W=96, stride=1
constexpr int B_ = 8, C_ = 256, H_ = 128, W_ = 96;
constexpr int HW_ = H_ * W_;

__device__ __forceinline__ float lrelu_f(float v) { return v > 0.f ? v : 0.1f * v; }

// ---------------------------------------------------------------------------
// Correlation + lrelu:  corr[b, dy*7+dx, y, x] =
//     lrelu( (1/256) * sum_c f1[b,c,y,x] * f2[b,c,y+dy-3,x+dx-3] )   (zero pad)
// Block: 384 threads = 24 pixel-groups(4px) x 4 dy-groups(2dy) x 4 rows.
// 256 blocks = 8 batches x 32 row-tiles (4 rows each).
// ---------------------------------------------------------------------------
constexpr int CR = 4;     // output rows per block
constexpr int F2R = 11;   // staged f2 rows (10 used + 1 dummy for dy=7 lane waste)
constexpr int CCH = 2;    // channels per LDS chunk

__global__ __launch_bounds__(384)
void corr_kernel(const float* __restrict__ f1, const float* __restrict__ f2,
                 float* __restrict__ corr)
{
    // pow2 strides so staging index math is shifts, rows 16B-aligned for b128
    __shared__ __align__(16) float s2[F2R][CCH][128];
    __shared__ __align__(16) float s1[CR][CCH][128];

    const int tid = threadIdx.x;
    const int pxg = tid % 24;          // 4-pixel group along x
    const int dygrp = (tid / 24) & 3;  // owns dy = {2g, 2g+1} (g=3: dy=6 + dummy 7)
    const int ty = tid / 96;           // row within tile
    const int x0 = pxg * 4;

    const int b = blockIdx.x >> 5;
    const int y0 = (blockIdx.x & 31) * CR;
    const int y = y0 + ty;

    float acc[2][7][4];
#pragma unroll
    for (int i = 0; i < 2; i++)
#pragma unroll
        for (int j = 0; j < 7; j++)
#pragma unroll
            for (int k = 0; k < 4; k++) acc[i][j][k] = 0.f;

    const float* f1b = f1 + b * C_ * HW_;
    const float* f2b = f2 + b * C_ * HW_;

    for (int cc = 0; cc < C_; cc += CCH) {
        __syncthreads();
        // stage f2 rows y0-3 .. y0+7 (11 rows), cols -3..98 at tile col 0..101
        for (int e = tid; e < F2R * CCH * 128; e += 384) {
            int r = e >> 8;
            int c = (e >> 7) & 1;
            int col = e & 127;
            int yg = y0 + r - 3;
            int xg = col - 3;
            float v = 0.f;
            if (yg >= 0 && yg < H_ && xg >= 0 && xg < W_)
                v = f2b[(cc + c) * HW_ + yg * W_ + xg];
            s2[r][c][col] = v;
        }
        // stage f1 rows y0..y0+3
        for (int e = tid; e < CR * CCH * 128; e += 384) {
            int r = e >> 8;
            int c = (e >> 7) & 1;
            int col = e & 127;
            if (col < W_)
                s1[r][c][col] = f1b[(cc + c) * HW_ + (y0 + r) * W_ + col];
        }
        __syncthreads();
#pragma unroll
        for (int c = 0; c < CCH; c++) {
            float4 v1 = *(const float4*)&s1[ty][c][x0];
            float v1a[4] = {v1.x, v1.y, v1.z, v1.w};
#pragma unroll
            for (int dyl = 0; dyl < 2; dyl++) {
                int row = ty + dygrp * 2 + dyl;          // <= 3+6+1 = 10
                const float* rp = &s2[row][c][x0];
                float4 a0 = *(const float4*)&rp[0];
                float4 a1 = *(const float4*)&rp[4];
                float4 a2 = *(const float4*)&rp[8];
                float iv[12] = {a0.x, a0.y, a0.z, a0.w, a1.x, a1.y, a1.z, a1.w,
                                a2.x, a2.y, a2.z, a2.w};
#pragma unroll
                for (int dx = 0; dx < 7; dx++)
#pragma unroll
                    for (int p = 0; p < 4; p++)
                        acc[dyl][dx][p] += v1a[p] * iv[p + dx];
            }
        }
    }

    const float scale = 1.f / (float)C_;
#pragma unroll
    for (int dyl = 0; dyl < 2; dyl++) {
        int dy = dygrp * 2 + dyl;
        if (dy > 6) continue;                 // dygrp==3 second half is dummy
#pragma unroll
        for (int dx = 0; dx < 7; dx++) {
            int d = dy * 7 + dx;
            float4 o;
            o.x = lrelu_f(acc[dyl][dx][0] * scale);
            o.y = lrelu_f(acc[dyl][dx][1] * scale);
            o.z = lrelu_f(acc[dyl][dx][2] * scale);
            o.w = lrelu_f(acc[dyl][dx][3] * scale);
            *(float4*)&corr[((b * 49 + d) * H_ + y) * W_ + x0] = o;
        }
    }
}

// ---------------------------------------------------------------------------
// 3x3 conv, pad 1, + bias (+ lrelu).  Register-tiled: each thread computes an
// 8-pixel x OCT-outchannel outer product.  Block: 12 strips x 4 rows x 4 oc
// groups = 192 threads; tile = full 96-wide row x 4 rows.
// grid.x = b*32 + ytile, grid.y = oc pass (OCP = 4*OCT ocs per pass).
// ---------------------------------------------------------------------------
template <int CIN, int COUT, int OCT, bool DOLRELU>
__global__ __launch_bounds__(192)
void conv3x3_kernel(const float* __restrict__ in, const float* __restrict__ wgt,
                    const float* __restrict__ bias, float* __restrict__ out)
{
    constexpr int G = 4, TH = 4, PX = 8, STRIPS = 12;
    constexpr int OCP = G * OCT;   // 32 or 16 (pow2)
    constexpr int CCH2 = 2;

    __shared__ __align__(16) float sin_[TH + 2][CCH2][128];
    __shared__ __align__(16) float sw_[9][CCH2][OCP];

    const int tid = threadIdx.x;
    const int strip = tid % STRIPS;
    const int ty = (tid / STRIPS) % TH;
    const int g = tid / (STRIPS * TH);

    const int b = blockIdx.x >> 5;
    const int y0 = (blockIdx.x & 31) * TH;
    const int oc0 = blockIdx.y * OCP;
    const int x0 = strip * PX;
    const int y = y0 + ty;

    float acc[OCT][PX];
#pragma unroll
    for (int j = 0; j < OCT; j++)
#pragma unroll
        for (int p = 0; p < PX; p++) acc[j][p] = 0.f;

    for (int cc = 0; cc < CIN; cc += CCH2) {
        __syncthreads();
        // stage input tile: rows y0-1 .. y0+4, cols -1..96 at tile col 0..97
        for (int e = tid; e < (TH + 2) * CCH2 * 128; e += 192) {
            int r = e >> 8;
            int c = (e >> 7) & 1;
            int col = e & 127;
            int yg = y0 + r - 1;
            int xg = col - 1;
            float v = 0.f;
            if (cc + c < CIN && yg >= 0 && yg < H_ && xg >= 0 && xg < W_)
                v = in[((b * CIN + cc + c) * H_ + yg) * W_ + xg];
            sin_[r][c][col] = v;
        }
        // stage weights for this pass's OCP ocs
        for (int e = tid; e < 9 * CCH2 * OCP; e += 192) {
            int t = e / (CCH2 * OCP);
            int rr = e - t * (CCH2 * OCP);
            int c = rr / OCP;
            int j = rr - c * OCP;
            float v = 0.f;
            if (cc + c < CIN)
                v = wgt[((oc0 + j) * CIN + cc + c) * 9 + t];
            sw_[t][c][j] = v;
        }
        __syncthreads();
#pragma unroll
        for (int c = 0; c < CCH2; c++) {
#pragma unroll
            for (int r = 0; r < 3; r++) {
                const float* rp = &sin_[ty + r][c][x0];
                float4 a0 = *(const float4*)&rp[0];
                float4 a1 = *(const float4*)&rp[4];
                float2 a2 = *(const float2*)&rp[8];
                float iv[10] = {a0.x, a0.y, a0.z, a0.w,
                                a1.x, a1.y, a1.z, a1.w, a2.x, a2.y};
#pragma unroll
                for (int s = 0; s < 3; s++) {
                    float wv[OCT];
#pragma unroll
                    for (int jj = 0; jj < OCT; jj += 4)
                        *(float4*)&wv[jj] =
                            *(const float4*)&sw_[r * 3 + s][c][g * OCT + jj];
#pragma unroll
                    for (int j = 0; j < OCT; j++)
#pragma unroll
                        for (int p = 0; p < PX; p++)
                            acc[j][p] += wv[j] * iv[p + s];
                }
            }
        }
    }

#pragma unroll
    for (int j = 0; j < OCT; j++) {
        int oc = oc0 + g * OCT + j;
        float bv = bias[oc];
        float o[PX];
#pragma unroll
        for (int p = 0; p < PX; p++) {
            float v = acc[j][p] + bv;
            o[p] = DOLRELU ? lrelu_f(v) : v;
        }
        float* op = &out[((b * COUT + oc) * H_ + y) * W_ + x0];
        *(float4*)&op[0] = make_float4(o[0], o[1], o[2], o[3]);
        *(float4*)&op[4] = make_float4(o[4], o[5], o[6], o[7]);
    }
}

// ---------------------------------------------------------------------------
// conv4: 32 -> 2 channels (flow), no lrelu.  Tiny; thread-per-pixel, weights
// fully in LDS, inputs via cache.
// ---------------------------------------------------------------------------
__global__ __launch_bounds__(256)
void conv4_kernel(const float* __restrict__ in, const float* __restrict__ wgt,
                  const float* __restrict__ bias, float* __restrict__ flow)
{
    __shared__ float s_w[2 * 32 * 9];
    __shared__ float s_b[2];
    const int tid = threadIdx.x;
    for (int e = tid; e < 2 * 32 * 9; e += 256) s_w[e] = wgt[e];
    if (tid < 2) s_b[tid] = bias[tid];
    __syncthreads();

    int pix = blockIdx.x * 256 + tid;   // 384 blocks cover 98304 pixels
    int b = pix / HW_;
    int rem = pix - b * HW_;
    int yy = rem / W_;
    int xx = rem - yy * W_;

    float a0 = s_b[0], a1 = s_b[1];
    const float* inb = in + b * 32 * HW_;
    for (int ci = 0; ci < 32; ci++) {
#pragma unroll
        for (int r = 0; r < 3; r++) {
            int yg = yy + r - 1;
            if (yg < 0 || yg >= H_) continue;
#pragma unroll
            for (int s = 0; s < 3; s++) {
                int xg = xx + s - 1;
                if (xg < 0 || xg >= W_) continue;
                float v = inb[ci * HW_ + yg * W_ + xg];
                a0 += v * s_w[(0 * 32 + ci) * 9 + r * 3 + s];
                a1 += v * s_w[(1 * 32 + ci) * 9 + r * 3 + s];
            }
        }
    }
    flow[(b * 2 + 0) * HW_ + rem] = a0;
    flow[(b * 2 + 1) * HW_ + rem] = a1;
}

// ---------------------------------------------------------------------------
// Warp: apply_offset + grid_sample fused.  The normalize/denormalize cancels:
//   x_s = clamp(x + flow_x, 0, W-1), y_s = clamp(y + flow_y, 0, H-1).
// Thread per pixel, loop over 256 channels (weights/indices hoisted).
// ---------------------------------------------------------------------------
__global__ __launch_bounds__(256)
void warp_kernel(const float* __restrict__ f2, const float* __restrict__ flow,
                 float* __restrict__ out)
{
    int pix = blockIdx.x * 256 + threadIdx.x;
    int b = pix / HW_;
    int rem = pix - b * HW_;
    int yy = rem / W_;
    int xx = rem - yy * W_;

    float fx = flow[(b * 2 + 0) * HW_ + rem];
    float fy = flow[(b * 2 + 1) * HW_ + rem];
    float xs = fminf(fmaxf((float)xx + fx, 0.f), (float)(W_ - 1));
    float ys = fminf(fmaxf((float)yy + fy, 0.f), (float)(H_ - 1));
    float x0f = floorf(xs), y0f = floorf(ys);
    int x0 = (int)x0f, y0 = (int)y0f;
    float wx = xs - x0f, wy = ys - y0f;
    int x1 = min(x0 + 1, W_ - 1), y1 = min(y0 + 1, H_ - 1);

    int i00 = y0 * W_ + x0, i01 = y0 * W_ + x1;
    int i10 = y1 * W_ + x0, i11 = y1 * W_ + x1;
    float w00 = (1.f - wx) * (1.f - wy), w01 = wx * (1.f - wy);
    float w10 = (1.f - wx) * wy, w11 = wx * wy;

    const float* base = f2 + b * C_ * HW_;
    float* ob = out + b * C_ * HW_ + rem;
#pragma unroll 4
    for (int c = 0; c < C_; c++) {
        const float* p = base + c * HW_;
        ob[c * HW_] = p[i00] * w00 + p[i01] * w01 + p[i10] * w10 + p[i11] * w11;
    }
}

// ---------------------------------------------------------------------------
extern "C" void kernel_launch(void* const* d_in, const int* in_sizes, int n_in,
                              void* d_out, int out_size, void* d_ws, size_t ws_size,
                              hipStream_t stream)
{
    (void)in_sizes; (void)n_in; (void)out_size; (void)ws_size;
    const float* feat1 = (const float*)d_in[0];
    const float* feat2 = (const float*)d_in[1];
    const float* w1 = (const float*)d_in[2];
    const float* b1 = (const float*)d_in[3];
    const float* w2 = (const float*)d_in[4];
    const float* b2 = (const float*)d_in[5];
    const float* w3 = (const float*)d_in[6];
    const float* b3 = (const float*)d_in[7];
    const float* w4 = (const float*)d_in[8];
    const float* b4 = (const float*)d_in[9];
    // d_in[10] = stride (always 1 for this problem)

    float* ws = (float*)d_ws;
    // Region plan (floats): R1 [0, 12582912) ; R2 [12582912, 18874368)
    float* R1 = ws;
    float* R2 = ws + 12582912;
    float* corr = R2;              // 8*49*12288  = 4,816,896
    float* h1 = R1;                // 8*128*12288 = 12,582,912
    float* h2 = R2;                // 8*64*12288  = 6,291,456 (corr dead)
    float* h3 = R1;                // 8*32*12288  = 3,145,728 (h1 dead)
    float* flow = R1 + 3145728;    // 8*2*12288   = 196,608
    float* out = (float*)d_out;

    corr_kernel<<<256, 384, 0, stream>>>(feat1, feat2, corr);
    conv3x3_kernel<49, 128, 8, true><<<dim3(256, 4), 192, 0, stream>>>(corr, w1, b1, h1);
    conv3x3_kernel<128, 64, 8, true><<<dim3(256, 2), 192, 0, stream>>>(h1, w2, b2, h2);
    conv3x3_kernel<64, 32, 4, true><<<dim3(256, 2), 192, 0, stream>>>(h2, w3, b3, h3);
    conv4_kernel<<<384, 256, 0, stream>>>(h3, w4, b4, flow);
    warp_kernel<<<384, 256, 0, stream>>>(feat2, flow, out);
}

// Round 2
// 1183.342 us; speedup vs baseline: 1.3752x; 1.3752x over previous
//
#include <hip/hip_runtime.h>

// Problem constants (setup_inputs): B=8, C=256, H=128, W=96, stride=1
constexpr int B_ = 8, C_ = 256, H_ = 128, W_ = 96;
constexpr int HW_ = H_ * W_;

__device__ __forceinline__ float lrelu_f(float v) { return v > 0.f ? v : 0.1f * v; }

// ---------------------------------------------------------------------------
// Correlation + lrelu:  corr[b, dy*7+dx, y, x] =
//     lrelu( (1/256) * sum_c f1[b,c,y,x] * f2[b,c,y+dy-3,x+dx-3] )  (zero pad)
//
// R1 redesign: 768 threads (12 waves) x 256 blocks -> 12 waves/CU (37.5% occ,
// was 18.75% cap). Ownership: 24 xgroups(4px) x 4 rows x 8 dy (dy==7 dummy).
// CCH=8 -> 32 iters (was 128): 4x fewer barriers. Staging counts divide 768
// exactly; bounds handled branch-free via clamp+select.
// LDS = 48K (f2) + 12K (f1) = 60 KB.
// ---------------------------------------------------------------------------
constexpr int CR = 4;     // output rows per block
constexpr int F2R = 12;   // staged f2 rows (11 used; 12 for exact divisibility)
constexpr int CCH = 8;    // channels per LDS chunk

__global__ __launch_bounds__(768)
void corr_kernel(const float* __restrict__ f1, const float* __restrict__ f2,
                 float* __restrict__ corr)
{
    __shared__ __align__(16) float s2[F2R][CCH][128];
    __shared__ __align__(16) float s1[CCH][CR][96];

    const int tid = threadIdx.x;
    const int pxg = tid % 24;          // 4-pixel group along x
    const int ty = (tid / 24) % CR;    // row within tile
    const int dy = tid / 96;           // 0..7 (7 is dummy)
    const int x0 = pxg * 4;

    const int b = blockIdx.x >> 5;
    const int y0 = (blockIdx.x & 31) * CR;
    const int y = y0 + ty;

    float acc[7][4];
#pragma unroll
    for (int j = 0; j < 7; j++)
#pragma unroll
        for (int k = 0; k < 4; k++) acc[j][k] = 0.f;

    const float* f1b = f1 + b * C_ * HW_;
    const float* f2b = f2 + b * C_ * HW_;

    for (int cc = 0; cc < C_; cc += CCH) {
        __syncthreads();
        // stage f2: 12 rows x 8 ch x 128 cols = 12288 = 16 * 768 (exact)
#pragma unroll
        for (int k = 0; k < 16; k++) {
            int e = k * 768 + tid;
            int col = e & 127;
            int c = (e >> 7) & 7;
            int r = e >> 10;           // 0..11
            int yg = y0 + r - 3;
            int xg = col - 3;
            bool valid = ((unsigned)yg < (unsigned)H_) && ((unsigned)xg < (unsigned)W_);
            int ygc = min(max(yg, 0), H_ - 1);
            int xgc = min(max(xg, 0), W_ - 1);
            float v = f2b[(cc + c) * HW_ + ygc * W_ + xgc];
            s2[r][c][col] = valid ? v : 0.f;
        }
        // stage f1: 8 ch x 4 rows x 96 cols = 3072 = 4 * 768 (exact)
#pragma unroll
        for (int k = 0; k < 4; k++) {
            int e = k * 768 + tid;
            int idx = e / 96;          // 0..31
            int col = e - idx * 96;
            int c = idx >> 2;
            int r = idx & 3;
            s1[c][r][col] = f1b[(cc + c) * HW_ + (y0 + r) * W_ + col];
        }
        __syncthreads();
#pragma unroll
        for (int c = 0; c < CCH; c++) {
            float4 v1 = *(const float4*)&s1[c][ty][x0];
            float v1a[4] = {v1.x, v1.y, v1.z, v1.w};
            const float* rp = &s2[ty + dy][c][x0];   // row <= 3+7 = 10 < 12
            float4 a0 = *(const float4*)&rp[0];
            float4 a1 = *(const float4*)&rp[4];
            float4 a2 = *(const float4*)&rp[8];
            float iv[12] = {a0.x, a0.y, a0.z, a0.w, a1.x, a1.y, a1.z, a1.w,
                            a2.x, a2.y, a2.z, a2.w};
#pragma unroll
            for (int dx = 0; dx < 7; dx++)
#pragma unroll
                for (int p = 0; p < 4; p++)
                    acc[dx][p] += v1a[p] * iv[p + dx];
        }
    }

    if (dy < 7) {
        const float scale = 1.f / (float)C_;
#pragma unroll
        for (int dx = 0; dx < 7; dx++) {
            int d = dy * 7 + dx;
            float4 o;
            o.x = lrelu_f(acc[dx][0] * scale);
            o.y = lrelu_f(acc[dx][1] * scale);
            o.z = lrelu_f(acc[dx][2] * scale);
            o.w = lrelu_f(acc[dx][3] * scale);
            *(float4*)&corr[((b * 49 + d) * H_ + y) * W_ + x0] = o;
        }
    }
}

// ---------------------------------------------------------------------------
// 3x3 conv, pad 1, + bias (+ lrelu).  Register-tiled: each thread computes an
// 8-pixel x OCT-outchannel outer product.  Block: 12 strips x 4 rows x 4 oc
// groups = 192 threads; tile = full 96-wide row x 4 rows.
// grid.x = b*32 + ytile, grid.y = oc pass (OCP = 4*OCT ocs per pass).
// ---------------------------------------------------------------------------
template <int CIN, int COUT, int OCT, bool DOLRELU>
__global__ __launch_bounds__(192)
void conv3x3_kernel(const float* __restrict__ in, const float* __restrict__ wgt,
                    const float* __restrict__ bias, float* __restrict__ out)
{
    constexpr int G = 4, TH = 4, PX = 8, STRIPS = 12;
    constexpr int OCP = G * OCT;   // 32 or 16 (pow2)
    constexpr int CCH2 = 2;

    __shared__ __align__(16) float sin_[TH + 2][CCH2][128];
    __shared__ __align__(16) float sw_[9][CCH2][OCP];

    const int tid = threadIdx.x;
    const int strip = tid % STRIPS;
    const int ty = (tid / STRIPS) % TH;
    const int g = tid / (STRIPS * TH);

    const int b = blockIdx.x >> 5;
    const int y0 = (blockIdx.x & 31) * TH;
    const int oc0 = blockIdx.y * OCP;
    const int x0 = strip * PX;
    const int y = y0 + ty;

    float acc[OCT][PX];
#pragma unroll
    for (int j = 0; j < OCT; j++)
#pragma unroll
        for (int p = 0; p < PX; p++) acc[j][p] = 0.f;

    for (int cc = 0; cc < CIN; cc += CCH2) {
        __syncthreads();
        // stage input tile: rows y0-1 .. y0+4, cols -1..96 at tile col 0..97
        for (int e = tid; e < (TH + 2) * CCH2 * 128; e += 192) {
            int r = e >> 8;
            int c = (e >> 7) & 1;
            int col = e & 127;
            int yg = y0 + r - 1;
            int xg = col - 1;
            float v = 0.f;
            if (cc + c < CIN && yg >= 0 && yg < H_ && xg >= 0 && xg < W_)
                v = in[((b * CIN + cc + c) * H_ + yg) * W_ + xg];
            sin_[r][c][col] = v;
        }
        // stage weights for this pass's OCP ocs
        for (int e = tid; e < 9 * CCH2 * OCP; e += 192) {
            int t = e / (CCH2 * OCP);
            int rr = e - t * (CCH2 * OCP);
            int c = rr / OCP;
            int j = rr - c * OCP;
            float v = 0.f;
            if (cc + c < CIN)
                v = wgt[((oc0 + j) * CIN + cc + c) * 9 + t];
            sw_[t][c][j] = v;
        }
        __syncthreads();
#pragma unroll
        for (int c = 0; c < CCH2; c++) {
#pragma unroll
            for (int r = 0; r < 3; r++) {
                const float* rp = &sin_[ty + r][c][x0];
                float4 a0 = *(const float4*)&rp[0];
                float4 a1 = *(const float4*)&rp[4];
                float2 a2 = *(const float2*)&rp[8];
                float iv[10] = {a0.x, a0.y, a0.z, a0.w,
                                a1.x, a1.y, a1.z, a1.w, a2.x, a2.y};
#pragma unroll
                for (int s = 0; s < 3; s++) {
                    float wv[OCT];
#pragma unroll
                    for (int jj = 0; jj < OCT; jj += 4)
                        *(float4*)&wv[jj] =
                            *(const float4*)&sw_[r * 3 + s][c][g * OCT + jj];
#pragma unroll
                    for (int j = 0; j < OCT; j++)
#pragma unroll
                        for (int p = 0; p < PX; p++)
                            acc[j][p] += wv[j] * iv[p + s];
                }
            }
        }
    }

#pragma unroll
    for (int j = 0; j < OCT; j++) {
        int oc = oc0 + g * OCT + j;
        float bv = bias[oc];
        float o[PX];
#pragma unroll
        for (int p = 0; p < PX; p++) {
            float v = acc[j][p] + bv;
            o[p] = DOLRELU ? lrelu_f(v) : v;
        }
        float* op = &out[((b * COUT + oc) * H_ + y) * W_ + x0];
        *(float4*)&op[0] = make_float4(o[0], o[1], o[2], o[3]);
        *(float4*)&op[4] = make_float4(o[4], o[5], o[6], o[7]);
    }
}

// ---------------------------------------------------------------------------
// conv4: 32 -> 2 channels (flow), no lrelu.  Tiny; thread-per-pixel, weights
// fully in LDS, inputs via cache.
// ---------------------------------------------------------------------------
__global__ __launch_bounds__(256)
void conv4_kernel(const float* __restrict__ in, const float* __restrict__ wgt,
                  const float* __restrict__ bias, float* __restrict__ flow)
{
    __shared__ float s_w[2 * 32 * 9];
    __shared__ float s_b[2];
    const int tid = threadIdx.x;
    for (int e = tid; e < 2 * 32 * 9; e += 256) s_w[e] = wgt[e];
    if (tid < 2) s_b[tid] = bias[tid];
    __syncthreads();

    int pix = blockIdx.x * 256 + tid;   // 384 blocks cover 98304 pixels
    int b = pix / HW_;
    int rem = pix - b * HW_;
    int yy = rem / W_;
    int xx = rem - yy * W_;

    float a0 = s_b[0], a1 = s_b[1];
    const float* inb = in + b * 32 * HW_;
    for (int ci = 0; ci < 32; ci++) {
#pragma unroll
        for (int r = 0; r < 3; r++) {
            int yg = yy + r - 1;
            if (yg < 0 || yg >= H_) continue;
#pragma unroll
            for (int s = 0; s < 3; s++) {
                int xg = xx + s - 1;
                if (xg < 0 || xg >= W_) continue;
                float v = inb[ci * HW_ + yg * W_ + xg];
                a0 += v * s_w[(0 * 32 + ci) * 9 + r * 3 + s];
                a1 += v * s_w[(1 * 32 + ci) * 9 + r * 3 + s];
            }
        }
    }
    flow[(b * 2 + 0) * HW_ + rem] = a0;
    flow[(b * 2 + 1) * HW_ + rem] = a1;
}

// ---------------------------------------------------------------------------
// Warp: apply_offset + grid_sample fused.  The normalize/denormalize cancels:
//   x_s = clamp(x + flow_x, 0, W-1), y_s = clamp(y + flow_y, 0, H-1).
// Thread per pixel, loop over 256 channels (weights/indices hoisted).
// ---------------------------------------------------------------------------
__global__ __launch_bounds__(256)
void warp_kernel(const float* __restrict__ f2, const float* __restrict__ flow,
                 float* __restrict__ out)
{
    int pix = blockIdx.x * 256 + threadIdx.x;
    int b = pix / HW_;
    int rem = pix - b * HW_;
    int yy = rem / W_;
    int xx = rem - yy * W_;

    float fx = flow[(b * 2 + 0) * HW_ + rem];
    float fy = flow[(b * 2 + 1) * HW_ + rem];
    float xs = fminf(fmaxf((float)xx + fx, 0.f), (float)(W_ - 1));
    float ys = fminf(fmaxf((float)yy + fy, 0.f), (float)(H_ - 1));
    float x0f = floorf(xs), y0f = floorf(ys);
    int x0 = (int)x0f, y0 = (int)y0f;
    float wx = xs - x0f, wy = ys - y0f;
    int x1 = min(x0 + 1, W_ - 1), y1 = min(y0 + 1, H_ - 1);

    int i00 = y0 * W_ + x0, i01 = y0 * W_ + x1;
    int i10 = y1 * W_ + x0, i11 = y1 * W_ + x1;
    float w00 = (1.f - wx) * (1.f - wy), w01 = wx * (1.f - wy);
    float w10 = (1.f - wx) * wy, w11 = wx * wy;

    const float* base = f2 + b * C_ * HW_;
    float* ob = out + b * C_ * HW_ + rem;
#pragma unroll 4
    for (int c = 0; c < C_; c++) {
        const float* p = base + c * HW_;
        ob[c * HW_] = p[i00] * w00 + p[i01] * w01 + p[i10] * w10 + p[i11] * w11;
    }
}

// ---------------------------------------------------------------------------
extern "C" void kernel_launch(void* const* d_in, const int* in_sizes, int n_in,
                              void* d_out, int out_size, void* d_ws, size_t ws_size,
                              hipStream_t stream)
{
    (void)in_sizes; (void)n_in; (void)out_size; (void)ws_size;
    const float* feat1 = (const float*)d_in[0];
    const float* feat2 = (const float*)d_in[1];
    const float* w1 = (const float*)d_in[2];
    const float* b1 = (const float*)d_in[3];
    const float* w2 = (const float*)d_in[4];
    const float* b2 = (const float*)d_in[5];
    const float* w3 = (const float*)d_in[6];
    const float* b3 = (const float*)d_in[7];
    const float* w4 = (const float*)d_in[8];
    const float* b4 = (const float*)d_in[9];
    // d_in[10] = stride (always 1 for this problem)

    float* ws = (float*)d_ws;
    // Region plan (floats): R1 [0, 12582912) ; R2 [12582912, 18874368)
    float* R1 = ws;
    float* R2 = ws + 12582912;
    float* corr = R2;              // 8*49*12288  = 4,816,896
    float* h1 = R1;                // 8*128*12288 = 12,582,912
    float* h2 = R2;                // 8*64*12288  = 6,291,456 (corr dead)
    float* h3 = R1;                // 8*32*12288  = 3,145,728 (h1 dead)
    float* flow = R1 + 3145728;    // 8*2*12288   = 196,608
    float* out = (float*)d_out;

    corr_kernel<<<256, 768, 0, stream>>>(feat1, feat2, corr);
    conv3x3_kernel<49, 128, 8, true><<<dim3(256, 4), 192, 0, stream>>>(corr, w1, b1, h1);
    conv3x3_kernel<128, 64, 8, true><<<dim3(256, 2), 192, 0, stream>>>(h1, w2, b2, h2);
    conv3x3_kernel<64, 32, 4, true><<<dim3(256, 2), 192, 0, stream>>>(h2, w3, b3, h3);
    conv4_kernel<<<384, 256, 0, stream>>>(h3, w4, b4, flow);
    warp_kernel<<<384, 256, 0, stream>>>(feat2, flow, out);
}

// Round 4
// 526.308 us; speedup vs baseline: 3.0921x; 2.2484x over previous
//
#include <hip/hip_runtime.h>

// Problem constants (setup_inputs): B=8, C=256, H=128, W=96, stride=1
constexpr int B_ = 8, C_ = 256, H_ = 128, W_ = 96;
constexpr int HW_ = H_ * W_;

typedef __bf16 bf16x8 __attribute__((ext_vector_type(8)));
typedef float f32x4 __attribute__((ext_vector_type(4)));

__device__ __forceinline__ float lrelu_f(float v) { return v > 0.f ? v : 0.1f * v; }
__device__ __forceinline__ ushort f2b(float v) {
    __bf16 h = (__bf16)v;
    return __builtin_bit_cast(ushort, h);
}
__device__ __forceinline__ float blo(unsigned u) {  // low ushort of packed pair -> f32
    return __builtin_bit_cast(float, u << 16);
}
__device__ __forceinline__ float bhi(unsigned u) {  // high ushort -> f32
    return __builtin_bit_cast(float, u & 0xffff0000u);
}

// ---------------------------------------------------------------------------
// Correlation + lrelu -> NHWC-64 bf16 (ch 0..48 data, 49..63 zero pad).
// Compute identical to R1 (768 thr, 12 waves, CCH=8). Epilogue transposes
// through s2 (exactly 49152 B = [4][96][64] ushort) for coalesced stores.
// ---------------------------------------------------------------------------
constexpr int CR = 4;
constexpr int F2R = 12;
constexpr int CCH = 8;

__global__ __launch_bounds__(768)
void corr_kernel(const float* __restrict__ f1, const float* __restrict__ f2,
                 ushort* __restrict__ corr_nhwc)
{
    __shared__ __align__(16) float s2[F2R][CCH][128];
    __shared__ __align__(16) float s1[CCH][CR][96];

    const int tid = threadIdx.x;
    const int pxg = tid % 24;
    const int ty = (tid / 24) % CR;
    const int dy = tid / 96;           // 0..7 (7 = pad-writer group)
    const int x0 = pxg * 4;

    const int b = blockIdx.x >> 5;
    const int y0 = (blockIdx.x & 31) * CR;

    float acc[7][4];
#pragma unroll
    for (int j = 0; j < 7; j++)
#pragma unroll
        for (int k = 0; k < 4; k++) acc[j][k] = 0.f;

    const float* f1p = f1 + b * C_ * HW_;
    const float* f2p = f2 + b * C_ * HW_;

    for (int cc = 0; cc < C_; cc += CCH) {
        __syncthreads();
#pragma unroll
        for (int k = 0; k < 16; k++) {
            int e = k * 768 + tid;
            int col = e & 127;
            int c = (e >> 7) & 7;
            int r = e >> 10;
            int yg = y0 + r - 3;
            int xg = col - 3;
            bool valid = ((unsigned)yg < (unsigned)H_) && ((unsigned)xg < (unsigned)W_);
            int ygc = min(max(yg, 0), H_ - 1);
            int xgc = min(max(xg, 0), W_ - 1);
            float v = f2p[(cc + c) * HW_ + ygc * W_ + xgc];
            s2[r][c][col] = valid ? v : 0.f;
        }
#pragma unroll
        for (int k = 0; k < 4; k++) {
            int e = k * 768 + tid;
            int idx = e / 96;
            int col = e - idx * 96;
            int c = idx >> 2;
            int r = idx & 3;
            s1[c][r][col] = f1p[(cc + c) * HW_ + (y0 + r) * W_ + col];
        }
        __syncthreads();
#pragma unroll
        for (int c = 0; c < CCH; c++) {
            float4 v1 = *(const float4*)&s1[c][ty][x0];
            float v1a[4] = {v1.x, v1.y, v1.z, v1.w};
            const float* rp = &s2[ty + dy][c][x0];
            float4 a0 = *(const float4*)&rp[0];
            float4 a1 = *(const float4*)&rp[4];
            float4 a2 = *(const float4*)&rp[8];
            float iv[12] = {a0.x, a0.y, a0.z, a0.w, a1.x, a1.y, a1.z, a1.w,
                            a2.x, a2.y, a2.z, a2.w};
#pragma unroll
            for (int dx = 0; dx < 7; dx++)
#pragma unroll
                for (int p = 0; p < 4; p++)
                    acc[dx][p] += v1a[p] * iv[p + dx];
        }
    }

    // Epilogue: transpose to NHWC-64 bf16 in LDS, then coalesced store.
    __syncthreads();
    ushort* t = (ushort*)&s2[0][0][0];          // [4][96][64] ushort = 49152 B
    const float scale = 1.f / 256.f;
    if (dy < 7) {
#pragma unroll
        for (int dx = 0; dx < 7; dx++)
#pragma unroll
            for (int p = 0; p < 4; p++)
                t[(ty * 96 + x0 + p) * 64 + dy * 7 + dx] =
                    f2b(lrelu_f(acc[dx][p] * scale));
    } else {
#pragma unroll
        for (int p = 0; p < 4; p++)
            for (int c = 49; c < 64; c++)
                t[(ty * 96 + x0 + p) * 64 + c] = 0;
    }
    __syncthreads();
    const uint4* src = (const uint4*)t;
    uint4* dst = (uint4*)(corr_nhwc + (size_t)(b * HW_ + y0 * W_) * 64);
    for (int e = tid; e < 3072; e += 768) dst[e] = src[e];
}

// ---------------------------------------------------------------------------
// Weight pack: [oc][ci][3][3] f32 -> [tap][oc][CIP] bf16 (ci >= CIN zeroed)
// ---------------------------------------------------------------------------
template <int CIN, int COUT, int CIP>
__global__ __launch_bounds__(256)
void pack_w(const float* __restrict__ w, ushort* __restrict__ wpk)
{
    int i = blockIdx.x * 256 + threadIdx.x;
    if (i >= 9 * COUT * CIP) return;
    int ci = i % CIP;
    int t = i / CIP;
    int oc = t % COUT;
    int tap = t / COUT;
    float v = (ci < CIN) ? w[(oc * CIN + ci) * 9 + tap] : 0.f;
    wpk[i] = f2b(v);
}

// ---------------------------------------------------------------------------
// MFMA shift-GEMM 3x3 conv (+bias+lrelu), NHWC bf16 in/out.
//   D[oc][px] = sum_{tap} sum_ci Wtap[oc][ci] * X[ci][px shifted by tap]
// Block: 4 waves (256 thr); wave ty handles row y0+ty, XT px, OCB ocs.
// Input tile (6 rows x XT+2 cols x CIP ci) staged ONCE in LDS, bf16,
// XOR-swizzled 16B units (2-way bank access on B-frag reads).
// A-frags: 16B per-lane loads from packed weights (L1/L2-resident).
// ---------------------------------------------------------------------------
template <int CIP, int COUT, int OCB, int XT, int XTILES>
__global__ __launch_bounds__(256)
void conv_mfma(const ushort* __restrict__ in, const ushort* __restrict__ wpk,
               const float* __restrict__ bias, ushort* __restrict__ out)
{
    constexpr int OCF = OCB / 16, PXF = XT / 16, COLS = XT + 2;
    constexpr int G = CIP / 8, KC = CIP / 32;
    __shared__ __align__(16) ushort sIn[6 * COLS * CIP];

    const int tid = threadIdx.x;
    const int lane = tid & 63;
    const int ty = tid >> 6;          // wave id == row within tile
    const int ln = lane & 15;
    const int lq = lane >> 4;

    const int gx = blockIdx.x;
    const int xt = gx % XTILES;
    const int yt = (gx / XTILES) % 32;
    const int b = gx / (XTILES * 32);
    const int oc0 = blockIdx.y * OCB;
    const int x0 = xt * XT;
    const int y0 = yt * 4;

    // ---- stage input tile: rows y0-1..y0+4, cols x0-1..x0+XT ----
    constexpr int NU = 6 * COLS * G;   // 16B units
    for (int e = tid; e < NU; e += 256) {
        int g = e & (G - 1);
        int pc = e / G;
        int col = pc % COLS;
        int rr = pc / COLS;
        int yg = y0 - 1 + rr;
        int xg = x0 - 1 + col;
        uint4 v = make_uint4(0, 0, 0, 0);
        if ((unsigned)yg < (unsigned)H_ && (unsigned)xg < (unsigned)W_)
            v = *(const uint4*)(in + ((size_t)(b * HW_ + yg * W_ + xg) * CIP + g * 8));
        int p = rr * COLS + col;
        *(uint4*)(sIn + (size_t)(p * G + (g ^ (p & 7))) * 8) = v;
    }
    __syncthreads();

    f32x4 acc[OCF][PXF];
#pragma unroll
    for (int of = 0; of < OCF; of++)
#pragma unroll
        for (int pf = 0; pf < PXF; pf++) {
            f32x4 z = {0.f, 0.f, 0.f, 0.f};
            acc[of][pf] = z;
        }

    const uint4* wq = (const uint4*)wpk;
    for (int kc = 0; kc < KC; kc++) {
        for (int tap = 0; tap < 9; tap++) {
            const int r = tap / 3, s = tap % 3;
            bf16x8 afr[OCF];
#pragma unroll
            for (int of = 0; of < OCF; of++) {
                int off = ((tap * COUT + oc0 + of * 16 + ln) * CIP + kc * 32 + lq * 8) >> 3;
                afr[of] = __builtin_bit_cast(bf16x8, wq[off]);
            }
#pragma unroll
            for (int pf = 0; pf < PXF; pf++) {
                int p = (ty + r) * COLS + (pf * 16 + ln + s);
                int g = kc * 4 + lq;
                uint4 bv = *(const uint4*)(sIn + (size_t)(p * G + (g ^ (p & 7))) * 8);
                bf16x8 bfr = __builtin_bit_cast(bf16x8, bv);
#pragma unroll
                for (int of = 0; of < OCF; of++)
                    acc[of][pf] = __builtin_amdgcn_mfma_f32_16x16x32_bf16(
                        afr[of], bfr, acc[of][pf], 0, 0, 0);
            }
        }
    }

    // ---- epilogue: D col = lane&15 (px), row = lq*4+reg (oc) ----
    const int y = y0 + ty;
#pragma unroll
    for (int of = 0; of < OCF; of++) {
        int ocb = oc0 + of * 16 + lq * 4;
        float4 bv = *(const float4*)(bias + ocb);
        float bs[4] = {bv.x, bv.y, bv.z, bv.w};
#pragma unroll
        for (int pf = 0; pf < PXF; pf++) {
            int x = x0 + pf * 16 + ln;
            ushort4 pk;
            pk.x = f2b(lrelu_f(acc[of][pf][0] + bs[0]));
            pk.y = f2b(lrelu_f(acc[of][pf][1] + bs[1]));
            pk.z = f2b(lrelu_f(acc[of][pf][2] + bs[2]));
            pk.w = f2b(lrelu_f(acc[of][pf][3] + bs[3]));
            *(ushort4*)(out + ((size_t)(b * HW_ + y * W_ + x) * COUT + ocb)) = pk;
        }
    }
}

// ---------------------------------------------------------------------------
// conv4: NHWC-32 bf16 -> 2ch flow (f32, NCHW), no lrelu.
// ---------------------------------------------------------------------------
__global__ __launch_bounds__(256)
void conv4_kernel(const ushort* __restrict__ in, const float* __restrict__ wgt,
                  const float* __restrict__ bias, float* __restrict__ flow)
{
    __shared__ float s_w[2 * 9 * 32];   // [oc][tap][ci]
    const int tid = threadIdx.x;
    for (int e = tid; e < 576; e += 256) {
        int ci = e & 31;
        int t = e >> 5;
        int tap = t % 9;
        int oc = t / 9;
        s_w[e] = wgt[(oc * 32 + ci) * 9 + tap];
    }
    __syncthreads();

    int pix = blockIdx.x * 256 + tid;
    int b = pix / HW_;
    int rem = pix - b * HW_;
    int yy = rem / W_;
    int xx = rem - yy * W_;

    float a0 = bias[0], a1 = bias[1];
    for (int tap = 0; tap < 9; tap++) {
        int r = tap / 3, s = tap % 3;
        int yg = yy + r - 1, xg = xx + s - 1;
        if ((unsigned)yg >= (unsigned)H_ || (unsigned)xg >= (unsigned)W_) continue;
        const uint4* p = (const uint4*)(in + (size_t)(b * HW_ + yg * W_ + xg) * 32);
        const float* w0 = &s_w[(0 * 9 + tap) * 32];
        const float* w1 = &s_w[(1 * 9 + tap) * 32];
#pragma unroll
        for (int q = 0; q < 4; q++) {
            uint4 v = p[q];
            unsigned uu[4] = {v.x, v.y, v.z, v.w};
#pragma unroll
            for (int h = 0; h < 4; h++) {
                int ci = q * 8 + h * 2;
                float vl = blo(uu[h]), vh = bhi(uu[h]);
                a0 += vl * w0[ci] + vh * w0[ci + 1];
                a1 += vl * w1[ci] + vh * w1[ci + 1];
            }
        }
    }
    flow[(b * 2 + 0) * HW_ + rem] = a0;
    flow[(b * 2 + 1) * HW_ + rem] = a1;
}

// ---------------------------------------------------------------------------
// Warp: x_s = clamp(x+flow_x,0,W-1), y_s = clamp(y+flow_y,0,H-1); bilinear.
// ---------------------------------------------------------------------------
__global__ __launch_bounds__(256)
void warp_kernel(const float* __restrict__ f2, const float* __restrict__ flow,
                 float* __restrict__ out)
{
    int pix = blockIdx.x * 256 + threadIdx.x;
    int b = pix / HW_;
    int rem = pix - b * HW_;
    int yy = rem / W_;
    int xx = rem - yy * W_;

    float fx = flow[(b * 2 + 0) * HW_ + rem];
    float fy = flow[(b * 2 + 1) * HW_ + rem];
    float xs = fminf(fmaxf((float)xx + fx, 0.f), (float)(W_ - 1));
    float ys = fminf(fmaxf((float)yy + fy, 0.f), (float)(H_ - 1));
    float x0f = floorf(xs), y0f = floorf(ys);
    int x0 = (int)x0f, y0 = (int)y0f;
    float wx = xs - x0f, wy = ys - y0f;
    int x1 = min(x0 + 1, W_ - 1), y1 = min(y0 + 1, H_ - 1);

    int i00 = y0 * W_ + x0, i01 = y0 * W_ + x1;
    int i10 = y1 * W_ + x0, i11 = y1 * W_ + x1;
    float w00 = (1.f - wx) * (1.f - wy), w01 = wx * (1.f - wy);
    float w10 = (1.f - wx) * wy, w11 = wx * wy;

    const float* base = f2 + b * C_ * HW_;
    float* ob = out + b * C_ * HW_ + rem;
#pragma unroll 4
    for (int c = 0; c < C_; c++) {
        const float* p = base + c * HW_;
        ob[c * HW_] = p[i00] * w00 + p[i01] * w01 + p[i10] * w10 + p[i11] * w11;
    }
}

// ---------------------------------------------------------------------------
extern "C" void kernel_launch(void* const* d_in, const int* in_sizes, int n_in,
                              void* d_out, int out_size, void* d_ws, size_t ws_size,
                              hipStream_t stream)
{
    (void)in_sizes; (void)n_in; (void)out_size; (void)ws_size;
    const float* feat1 = (const float*)d_in[0];
    const float* feat2 = (const float*)d_in[1];
    const float* w1 = (const float*)d_in[2];
    const float* b1 = (const float*)d_in[3];
    const float* w2 = (const float*)d_in[4];
    const float* b2 = (const float*)d_in[5];
    const float* w3 = (const float*)d_in[6];
    const float* b3 = (const float*)d_in[7];
    const float* w4 = (const float*)d_in[8];
    const float* b4 = (const float*)d_in[9];

    // Workspace layout (bytes, all 256-aligned)
    char* ws = (char*)d_ws;
    ushort* corr_nhwc = (ushort*)(ws);                       // 98304*64*2  = 12,582,912
    ushort* h1 = (ushort*)(ws + 12582912);                   // 98304*128*2 = 25,165,824
    ushort* h2 = (ushort*)(ws + 37748736);                   // 98304*64*2  = 12,582,912
    ushort* h3 = (ushort*)(ws + 50331648);                   // 98304*32*2  =  6,291,456
    float* flow = (float*)(ws + 56623104);                   // 196608*4    =    786,432
    ushort* wpk1 = (ushort*)(ws + 57409536);                 // 73728*2     =    147,456
    ushort* wpk2 = (ushort*)(ws + 57556992);                 // 73728*2     =    147,456
    ushort* wpk3 = (ushort*)(ws + 57704448);                 // 18432*2     =     36,864
    float* out = (float*)d_out;

    pack_w<49, 128, 64><<<288, 256, 0, stream>>>(w1, wpk1);
    pack_w<128, 64, 128><<<288, 256, 0, stream>>>(w2, wpk2);
    pack_w<64, 32, 64><<<72, 256, 0, stream>>>(w3, wpk3);

    corr_kernel<<<256, 768, 0, stream>>>(feat1, feat2, corr_nhwc);
    // conv1: 49(->64) -> 128, tiles 48px, oc passes of 64
    conv_mfma<64, 128, 64, 48, 2><<<dim3(512, 2), 256, 0, stream>>>(corr_nhwc, wpk1, b1, h1);
    // conv2: 128 -> 64, tiles 32px
    conv_mfma<128, 64, 64, 32, 3><<<dim3(768, 1), 256, 0, stream>>>(h1, wpk2, b2, h2);
    // conv3: 64 -> 32, tiles 48px
    conv_mfma<64, 32, 32, 48, 2><<<dim3(512, 1), 256, 0, stream>>>(h2, wpk3, b3, h3);
    conv4_kernel<<<384, 256, 0, stream>>>(h3, w4, b4, flow);
    warp_kernel<<<384, 256, 0, stream>>>(feat2, flow, out);
}